// Round 9
// baseline (5534.285 us; speedup 1.0000x reference)
//
#include <hip/hip_runtime.h>

#define B_   256
#define T_   512
#define IN_  34
#define H_   80
#define L_   10
#define NC_  5
#define G4   320
#define TPB  640
#define CH   64         // chunk timesteps (xp must fit LDS)
#define NCH  8          // T_/CH
#define XPG  84         // gate block padded 80->84 (bank decorrelation)

typedef float f4 __attribute__((ext_vector_type(4)));

__device__ __forceinline__ float sigm(float x) { return 1.f / (1.f + __expf(-x)); }

template <int CTRL>
__device__ __forceinline__ float dpp_add(float v) {
    int o = __builtin_amdgcn_update_dpp(0, __float_as_int(v), CTRL, 0xF, 0xF, true);
    return v + __int_as_float(o);
}
// sum over the 4-lane quad (s4 slices live in quad-aligned lanes)
__device__ __forceinline__ float reduce4(float v) {
    v = dpp_add<0xB1>(v);   // quad_perm xor 1
    v = dpp_add<0x4E>(v);   // quad_perm xor 2
    return v;
}
__device__ __forceinline__ float swz_xor4(float v) {
    return __int_as_float(__builtin_amdgcn_ds_swizzle(__float_as_int(v), 0x101F)); // xor-4
}

#define PIN4(W) asm volatile("" : "+v"(W))

// w1buf: phase-1 weights  [l][kh][j<10][row<320] float4 ; elem = W_ih[l][row][kh*40+4j+c] (layer0 zero-padded)
// w2buf: phase-2 weights  [l][j<10][tid<640] float4     ; row = gpair*160+(j>=5)*80+e, k = 20*s4+4*(j%5)+c
// bbuf : b_ih+b_hh        [l][320]
__global__ void prep_kernel(const float* __restrict__ Wih0, const float* __restrict__ WihR,
                            const float* __restrict__ Whh,  const float* __restrict__ bih,
                            const float* __restrict__ bhh,
                            float* __restrict__ w1, float* __restrict__ w2,
                            float* __restrict__ bbuf) {
    int idx = blockIdx.x * 256 + threadIdx.x;
    const int NW = L_ * 2 * 10 * G4 * 4;   // 256000
    if (idx < NW) {
        int c = idx & 3, f = idx >> 2;
        int row = f % G4, j = (f / G4) % 10, kh = (f / (G4 * 10)) % 2, l = f / (G4 * 20);
        int k = kh * 40 + 4 * j + c;
        float v;
        if (l == 0) v = (k < IN_) ? Wih0[row * IN_ + k] : 0.f;
        else        v = WihR[((size_t)(l - 1) * G4 + row) * H_ + k];
        w1[idx] = v;

        int tid = f % TPB, j2 = (f / TPB) % 10, l2 = f / (TPB * 10);
        int u = tid & 7, e = tid >> 3;
        int row2 = (u >> 2) * 160 + (j2 >= 5 ? H_ : 0) + e;
        int k2 = 20 * (u & 3) + 4 * (j2 % 5) + c;
        w2[idx] = Whh[((size_t)l2 * G4 + row2) * H_ + k2];
    }
    if (idx < L_ * G4) bbuf[idx] = bih[idx] + bhh[idx];
}

__global__ __launch_bounds__(TPB, 1) void lstm_stack_kernel(
    const float* __restrict__ x,
    const float* __restrict__ w1buf,
    const float* __restrict__ w2buf,
    const float* __restrict__ bbuf,
    const float* __restrict__ fcw,
    const float* __restrict__ fcb,
    float* __restrict__ out)
{
    const int b   = blockIdx.x;
    const int tid = threadIdx.x;       // 0..639
    const int u = tid & 7, e = tid >> 3;
    const int gpair = u >> 2, s4 = u & 3;
    const float gpairf = (float)gpair;
    const int row1 = tid % G4, thalf = tid / G4;
    const int g1 = row1 / H_, e1 = row1 % H_;

    __shared__ __align__(16) float hist[CH][H_];
    __shared__ __align__(16) float xp[CH][4][XPG];
    __shared__ __align__(16) float hs[2][H_];
    __shared__ float hstate[L_][H_];
    __shared__ float cstate[L_][H_];

    for (int j = tid; j < L_ * H_; j += TPB) {
        (&hstate[0][0])[j] = 0.f;
        (&cstate[0][0])[j] = 0.f;
    }

    const float* hsa = &hs[0][0] + 20 * s4;
    const float* hsb = &hs[1][0] + 20 * s4;

    for (int c = 0; c < NCH; ++c) {
        __syncthreads();
        const float* xsrc = x + ((size_t)b * T_ + (size_t)c * CH) * IN_;
        for (int j = tid; j < CH * IN_; j += TPB) hist[j / IN_][j % IN_] = xsrc[j];
        for (int j = tid; j < CH * (H_ - IN_); j += TPB)
            hist[j / (H_ - IN_)][IN_ + j % (H_ - IN_)] = 0.f;
        __syncthreads();

        for (int l = 0; l < L_; ++l) {
            // ---------------- PHASE 1: xp[t][row] = bias + W_ih . hist[t] ----------------
            {
                const float bias1 = bbuf[l * G4 + row1];
#pragma unroll
                for (int kh = 0; kh < 2; ++kh) {
                    const f4* wp = (const f4*)w1buf + ((size_t)(l * 2 + kh) * 10) * G4 + row1;
                    f4 q0 = wp[0 * G4], q1 = wp[1 * G4], q2 = wp[2 * G4], q3 = wp[3 * G4], q4 = wp[4 * G4];
                    f4 q5 = wp[5 * G4], q6 = wp[6 * G4], q7 = wp[7 * G4], q8 = wp[8 * G4], q9 = wp[9 * G4];
                    PIN4(q0); PIN4(q1); PIN4(q2); PIN4(q3); PIN4(q4);
                    PIN4(q5); PIN4(q6); PIN4(q7); PIN4(q8); PIN4(q9);
                    for (int tt = 0; tt < CH / 2; ++tt) {
                        const int t = thalf * (CH / 2) + tt;
                        const f4* hv = (const f4*)&hist[t][0] + kh * 10;
                        float a0 = kh ? xp[t][g1][e1] : bias1;
                        float a1 = 0.f, a2 = 0.f, a3 = 0.f;
#define P1(Q, J) { f4 v = hv[J]; a0 += Q.x * v.x; a1 += Q.y * v.y; a2 += Q.z * v.z; a3 += Q.w * v.w; }
                        P1(q0, 0) P1(q1, 1) P1(q2, 2) P1(q3, 3) P1(q4, 4)
                        P1(q5, 5) P1(q6, 6) P1(q7, 7) P1(q8, 8) P1(q9, 9)
#undef P1
                        xp[t][g1][e1] = (a0 + a1) + (a2 + a3);
                    }
                }
            }
            if (tid < H_) hs[0][tid] = hstate[l][tid];
            float creg = cstate[l][e];
            __syncthreads();

            // ---------------- PHASE 2: serial scan over the chunk ----------------
            const f4* wp2 = (const f4*)w2buf + (size_t)l * 10 * TPB + tid;
            f4 z0 = wp2[0 * TPB], z1 = wp2[1 * TPB], z2 = wp2[2 * TPB], z3 = wp2[3 * TPB], z4 = wp2[4 * TPB];
            f4 z5 = wp2[5 * TPB], z6 = wp2[6 * TPB], z7 = wp2[7 * TPB], z8 = wp2[8 * TPB], z9 = wp2[9 * TPB];
            PIN4(z0); PIN4(z1); PIN4(z2); PIN4(z3); PIN4(z4);
            PIN4(z5); PIN4(z6); PIN4(z7); PIN4(z8); PIN4(z9);

            float hcur = 0.f;
#define STEP(T, PAR) { \
                const f4* vp = (const f4*)((PAR) ? hsb : hsa); \
                f4 v0 = vp[0], v1 = vp[1], v2 = vp[2], v3 = vp[3], v4 = vp[4]; \
                float xa = xp[T][2 * gpair][e]; \
                float xb = xp[T][2 * gpair + 1][e]; \
                if (s4) { xa = 0.f; xb = 0.f; }   /* xp term must enter the quad-sum ONCE */ \
                float a0 = xa, a1 = 0.f, a2 = 0.f, a3 = 0.f; \
                float b0 = xb, b1 = 0.f, b2 = 0.f, b3 = 0.f; \
                a0 += z0.x * v0.x; a1 += z0.y * v0.y; a2 += z0.z * v0.z; a3 += z0.w * v0.w; \
                a0 += z1.x * v1.x; a1 += z1.y * v1.y; a2 += z1.z * v1.z; a3 += z1.w * v1.w; \
                a0 += z2.x * v2.x; a1 += z2.y * v2.y; a2 += z2.z * v2.z; a3 += z2.w * v2.w; \
                a0 += z3.x * v3.x; a1 += z3.y * v3.y; a2 += z3.z * v3.z; a3 += z3.w * v3.w; \
                a0 += z4.x * v4.x; a1 += z4.y * v4.y; a2 += z4.z * v4.z; a3 += z4.w * v4.w; \
                b0 += z5.x * v0.x; b1 += z5.y * v0.y; b2 += z5.z * v0.z; b3 += z5.w * v0.w; \
                b0 += z6.x * v1.x; b1 += z6.y * v1.y; b2 += z6.z * v1.z; b3 += z6.w * v1.w; \
                b0 += z7.x * v2.x; b1 += z7.y * v2.y; b2 += z7.z * v2.z; b3 += z7.w * v2.w; \
                b0 += z8.x * v3.x; b1 += z8.y * v3.y; b2 += z8.z * v3.z; b3 += z8.w * v3.w; \
                b0 += z9.x * v4.x; b1 += z9.y * v4.y; b2 += z9.z * v4.z; b3 += z9.w * v4.w; \
                float A = (a0 + a1) + (a2 + a3); \
                float Bv = (b0 + b1) + (b2 + b3); \
                A = reduce4(A); Bv = reduce4(Bv); \
                float sA = sigm(A + gpairf * A); \
                float gA = __builtin_fmaf(gpairf, sA, sA) - gpairf; \
                float gB = sigm(Bv); \
                float pA = swz_xor4(gA); \
                float pB = swz_xor4(gB); \
                creg = gB * creg + gA * pA; \
                float sC = sigm(creg + creg); \
                float th = __builtin_fmaf(2.f, sC, -1.f); \
                hcur = pB * th; \
                if (u == 0) { hs[(PAR) ^ 1][e] = hcur; hist[T][e] = hcur; } \
                __syncthreads(); \
            }
            for (int t2 = 0; t2 < CH; t2 += 2) {
                STEP(t2, 0)
                STEP(t2 + 1, 1)
            }
#undef STEP
            if (u == 0) { hstate[l][e] = hcur; cstate[l][e] = creg; }
        }
    }

    __syncthreads();
    if (tid < NC_) {
        float acc = fcb[tid];
#pragma unroll
        for (int j = 0; j < H_; ++j) acc += fcw[tid * H_ + j] * hstate[L_ - 1][j];
        out[b * NC_ + tid] = acc;
    }
}

extern "C" void kernel_launch(void* const* d_in, const int* in_sizes, int n_in,
                              void* d_out, int out_size, void* d_ws, size_t ws_size,
                              hipStream_t stream) {
    const float* x    = (const float*)d_in[0];
    const float* Wih0 = (const float*)d_in[1];
    const float* WihR = (const float*)d_in[2];
    const float* Whh  = (const float*)d_in[3];
    const float* bih  = (const float*)d_in[4];
    const float* bhh  = (const float*)d_in[5];
    const float* fcw  = (const float*)d_in[6];
    const float* fcb  = (const float*)d_in[7];

    float* w1buf = (float*)d_ws;
    float* w2buf = w1buf + 256000;
    float* bbuf  = w1buf + 512000;

    prep_kernel<<<dim3(1000), dim3(256), 0, stream>>>(
        Wih0, WihR, Whh, bih, bhh, w1buf, w2buf, bbuf);

    lstm_stack_kernel<<<dim3(B_), dim3(TPB), 0, stream>>>(
        x, w1buf, w2buf, bbuf, fcw, fcb, (float*)d_out);
}

// Round 10
// 3099.133 us; speedup vs baseline: 1.7858x; 1.7858x over previous
//
#include <hip/hip_runtime.h>

#define B_   256
#define T_   512
#define IN_  34
#define H_   80
#define L_   10
#define NC_  5
#define G4   320
#define TPB  640        // 80 e-elements x 8 K-slices

typedef _Float16 h2 __attribute__((ext_vector_type(2)));
typedef _Float16 h4 __attribute__((ext_vector_type(4)));

__device__ __forceinline__ float sigm(float x) {
    return __builtin_amdgcn_rcpf(1.f + __expf(-x));
}
__device__ __forceinline__ float tanh2(float x) {   // tanh(x) = 2*sigm(2x) - 1
    return __builtin_fmaf(2.f, sigm(x + x), -1.f);
}

template <int CTRL>
__device__ __forceinline__ float dpp_add(float v) {
    int o = __builtin_amdgcn_update_dpp(0, __float_as_int(v), CTRL, 0xF, 0xF, true);
    return v + __int_as_float(o);
}
// sum across the 8-lane slice group (lane bits 0..2); {xor1, xor2, xor7} generate it
__device__ __forceinline__ float reduce8(float v) {
    v = dpp_add<0xB1>(v);    // quad_perm xor 1
    v = dpp_add<0x4E>(v);    // quad_perm xor 2
    v = dpp_add<0x141>(v);   // row_half_mirror = xor 7
    return v;
}

__device__ __forceinline__ h2 bc(unsigned u) { return __builtin_bit_cast(h2, u); }
__device__ __forceinline__ h2 lo2(h4 v) { return __builtin_shufflevector(v, v, 0, 1); }
__device__ __forceinline__ h2 hi2(h4 v) { return __builtin_shufflevector(v, v, 2, 3); }

// w2 layout: uint4 index ((l*10 + n)*640 + tid); dword j = n*4+c encodes gate g=j/10,
// q=j%10: f16 pair (k0, k0+1), k0 = (s<4 ? 20*s : 20*(s-4)) + 2*q, row = g*80+e.
// s<4 -> input-side weights (layer0 zero-padded beyond 34), s>=4 -> W_hh.
__global__ void prep_kernel(const float* __restrict__ Wih0, const float* __restrict__ WihR,
                            const float* __restrict__ Whh,  const float* __restrict__ bih,
                            const float* __restrict__ bhh,
                            unsigned* __restrict__ w2, float* __restrict__ bbuf) {
    int idx = blockIdx.x * 256 + threadIdx.x;          // dword index
    const int ND = L_ * 10 * TPB * 4;                  // 256000 dwords
    if (idx < ND) {
        int tid = (idx >> 2) % TPB;
        int n   = ((idx >> 2) / TPB) % 10;
        int l   = (idx >> 2) / (TPB * 10);
        int j   = n * 4 + (idx & 3);
        int g = j / 10, q = j % 10;
        int e = tid >> 3, s = tid & 7;
        int row = g * H_ + e;
        int k0 = (s < 4 ? 20 * s : 20 * (s - 4)) + 2 * q;
        float w0, w1;
        if (s < 4) {
            if (l == 0) {
                w0 = (k0     < IN_) ? Wih0[row * IN_ + k0]     : 0.f;
                w1 = (k0 + 1 < IN_) ? Wih0[row * IN_ + k0 + 1] : 0.f;
            } else {
                w0 = WihR[((size_t)(l - 1) * G4 + row) * H_ + k0];
                w1 = WihR[((size_t)(l - 1) * G4 + row) * H_ + k0 + 1];
            }
        } else {
            w0 = Whh[((size_t)l * G4 + row) * H_ + k0];
            w1 = Whh[((size_t)l * G4 + row) * H_ + k0 + 1];
        }
        h2 p; p[0] = (_Float16)w0; p[1] = (_Float16)w1;
        w2[idx] = __builtin_bit_cast(unsigned, p);
    }
    if (idx < L_ * G4) bbuf[idx] = bih[idx] + bhh[idx];
}

__global__ __launch_bounds__(TPB, 1) void lstm_stack_kernel(
    const float* __restrict__ x,      // [B,T,34]
    const uint4* __restrict__ w2,     // packed f16x2 weights
    const float* __restrict__ bbuf,   // [10][320]
    const float* __restrict__ fcw,    // [5,80]
    const float* __restrict__ fcb,    // [5]
    float* __restrict__ out)          // [B,5]
{
    const int b   = blockIdx.x;
    const int tid = threadIdx.x;      // 0..639
    const int e   = tid >> 3;         // h element 0..79
    const int s   = tid & 7;          // K slice (0-3: input side, 4-7: hidden side)

    __shared__ __align__(16) _Float16 hist[T_][H_];   // 80 KB: x (f16) then h history
    __shared__ __align__(16) _Float16 hs[2][H_];      // h(t-1) ping-pong

    // ---- stage x -> f16 hist (zero-pad 34..79) ----
    for (int j = tid; j < T_ * H_; j += TPB) {
        int t = j / H_, k = j % H_;
        float v = (k < IN_) ? x[((size_t)b * T_ + t) * IN_ + k] : 0.f;
        hist[t][k] = (_Float16)v;
    }

    for (int l = 0; l < L_; ++l) {
        // ---- weights for this layer: 10 coalesced uint4 loads, resident all layer ----
        const uint4* wp = w2 + (size_t)l * 10 * TPB + tid;
        uint4 W0 = wp[0 * TPB], W1 = wp[1 * TPB], W2 = wp[2 * TPB], W3 = wp[3 * TPB], W4 = wp[4 * TPB];
        uint4 W5 = wp[5 * TPB], W6 = wp[6 * TPB], W7 = wp[7 * TPB], W8 = wp[8 * TPB], W9 = wp[9 * TPB];

        const float bi = (s == 0) ? bbuf[l * G4 + 0 * H_ + e] : 0.f;
        const float bf = (s == 0) ? bbuf[l * G4 + 1 * H_ + e] : 0.f;
        const float bg = (s == 0) ? bbuf[l * G4 + 2 * H_ + e] : 0.f;
        const float bo = (s == 0) ? bbuf[l * G4 + 3 * H_ + e] : 0.f;

        if (tid < 40) ((unsigned*)&hs[0][0])[tid] = 0;   // h(-1) = 0 (80 f16)
        __syncthreads();

        float creg = 0.f;
        _Float16 h16 = (_Float16)0.f;
        int par = 0;

#pragma unroll 2
        for (int t = 0; t < T_; ++t) {
            if (t && s == 0) hist[t - 1][e] = h16;   // deferred history write (safe: t-1 done)

            const h4* vp = (s < 4) ? (const h4*)(&hist[t][0] + 20 * s)
                                   : (const h4*)(&hs[par][0] + 20 * (s - 4));
            h4 v0 = vp[0], v1 = vp[1], v2 = vp[2], v3 = vp[3], v4 = vp[4];
            h2 p0 = lo2(v0), p1 = hi2(v0), p2 = lo2(v1), p3 = hi2(v1), p4 = lo2(v2);
            h2 p5 = hi2(v2), p6 = lo2(v3), p7 = hi2(v3), p8 = lo2(v4), p9 = hi2(v4);

            float aI = bi, aF = bf, aG = bg, aO = bo;
#define D(acc, W, C, P) acc = __builtin_amdgcn_fdot2(bc(W.C), P, acc, false);
            D(aI, W0, x, p0) D(aI, W0, y, p1) D(aI, W0, z, p2) D(aI, W0, w, p3)
            D(aI, W1, x, p4) D(aI, W1, y, p5) D(aI, W1, z, p6) D(aI, W1, w, p7)
            D(aI, W2, x, p8) D(aI, W2, y, p9)
            D(aF, W2, z, p0) D(aF, W2, w, p1)
            D(aF, W3, x, p2) D(aF, W3, y, p3) D(aF, W3, z, p4) D(aF, W3, w, p5)
            D(aF, W4, x, p6) D(aF, W4, y, p7) D(aF, W4, z, p8) D(aF, W4, w, p9)
            D(aG, W5, x, p0) D(aG, W5, y, p1) D(aG, W5, z, p2) D(aG, W5, w, p3)
            D(aG, W6, x, p4) D(aG, W6, y, p5) D(aG, W6, z, p6) D(aG, W6, w, p7)
            D(aG, W7, x, p8) D(aG, W7, y, p9)
            D(aO, W7, z, p0) D(aO, W7, w, p1)
            D(aO, W8, x, p2) D(aO, W8, y, p3) D(aO, W8, z, p4) D(aO, W8, w, p5)
            D(aO, W9, x, p6) D(aO, W9, y, p7) D(aO, W9, z, p8) D(aO, W9, w, p9)
#undef D
            aI = reduce8(aI); aF = reduce8(aF); aG = reduce8(aG); aO = reduce8(aO);

            float gi = sigm(aI), gf = sigm(aF), gg = tanh2(aG), go = sigm(aO);
            creg = gf * creg + gi * gg;
            float h = go * tanh2(creg);
            h16 = (_Float16)h;

            if (s == 0) hs[par ^ 1][e] = h16;
            __syncthreads();
            par ^= 1;
        }
        if (s == 0) hist[T_ - 1][e] = h16;   // flush last step
        __syncthreads();
    }

    // ---- fc on final hidden state ----
    if (tid < NC_) {
        float acc = fcb[tid];
#pragma unroll
        for (int j = 0; j < H_; ++j) acc += fcw[tid * H_ + j] * (float)hist[T_ - 1][j];
        out[b * NC_ + tid] = acc;
    }
}

extern "C" void kernel_launch(void* const* d_in, const int* in_sizes, int n_in,
                              void* d_out, int out_size, void* d_ws, size_t ws_size,
                              hipStream_t stream) {
    const float* x    = (const float*)d_in[0];
    const float* Wih0 = (const float*)d_in[1];
    const float* WihR = (const float*)d_in[2];
    const float* Whh  = (const float*)d_in[3];
    const float* bih  = (const float*)d_in[4];
    const float* bhh  = (const float*)d_in[5];
    const float* fcw  = (const float*)d_in[6];
    const float* fcb  = (const float*)d_in[7];

    unsigned* w2 = (unsigned*)d_ws;           // 256000 dwords
    float* bbuf  = (float*)(w2 + 256000);     // 3200 floats

    prep_kernel<<<dim3(1000), dim3(256), 0, stream>>>(
        Wih0, WihR, Whh, bih, bhh, w2, bbuf);

    lstm_stack_kernel<<<dim3(B_), dim3(TPB), 0, stream>>>(
        x, (const uint4*)w2, bbuf, fcw, fcb, (float*)d_out);
}

// Round 11
// 2713.612 us; speedup vs baseline: 2.0395x; 1.1421x over previous
//
#include <hip/hip_runtime.h>

#define B_   256
#define T_   512
#define IN_  34
#define H_   80
#define L_   10
#define NC_  5
#define G4   320
#define TPB  640        // 80 e-elements x 8 K-slices
#define HP   84         // hist row padded 80 -> 84 f16 (168 B: bank-rotates 10/row)

typedef _Float16 h2 __attribute__((ext_vector_type(2)));
typedef _Float16 h4 __attribute__((ext_vector_type(4)));

template <int CTRL>
__device__ __forceinline__ float dpp_mov(float v) {
    return __int_as_float(__builtin_amdgcn_update_dpp(0, __float_as_int(v), CTRL, 0xF, 0xF, true));
}
__device__ __forceinline__ h2 bc(unsigned u) { return __builtin_bit_cast(h2, u); }
__device__ __forceinline__ h2 lo2(h4 v) { return __builtin_shufflevector(v, v, 0, 1); }
__device__ __forceinline__ h2 hi2(h4 v) { return __builtin_shufflevector(v, v, 2, 3); }

// w2 layout: uint4 index ((l*10 + n)*640 + tid); dword j = n*4+c encodes gate g=j/10,
// q=j%10: f16 pair (k0, k0+1), k0 = (s<4 ? 20*s : 20*(s-4)) + 2*q, row = g*80+e.
// s<4 -> input-side weights (layer0 zero-padded beyond 34), s>=4 -> W_hh.
__global__ void prep_kernel(const float* __restrict__ Wih0, const float* __restrict__ WihR,
                            const float* __restrict__ Whh,  const float* __restrict__ bih,
                            const float* __restrict__ bhh,
                            unsigned* __restrict__ w2, float* __restrict__ bbuf) {
    int idx = blockIdx.x * 256 + threadIdx.x;          // dword index
    const int ND = L_ * 10 * TPB * 4;                  // 256000 dwords
    if (idx < ND) {
        int tid = (idx >> 2) % TPB;
        int n   = ((idx >> 2) / TPB) % 10;
        int l   = (idx >> 2) / (TPB * 10);
        int j   = n * 4 + (idx & 3);
        int g = j / 10, q = j % 10;
        int e = tid >> 3, s = tid & 7;
        int row = g * H_ + e;
        int k0 = (s < 4 ? 20 * s : 20 * (s - 4)) + 2 * q;
        float w0, w1;
        if (s < 4) {
            if (l == 0) {
                w0 = (k0     < IN_) ? Wih0[row * IN_ + k0]     : 0.f;
                w1 = (k0 + 1 < IN_) ? Wih0[row * IN_ + k0 + 1] : 0.f;
            } else {
                w0 = WihR[((size_t)(l - 1) * G4 + row) * H_ + k0];
                w1 = WihR[((size_t)(l - 1) * G4 + row) * H_ + k0 + 1];
            }
        } else {
            w0 = Whh[((size_t)l * G4 + row) * H_ + k0];
            w1 = Whh[((size_t)l * G4 + row) * H_ + k0 + 1];
        }
        h2 p; p[0] = (_Float16)w0; p[1] = (_Float16)w1;
        w2[idx] = __builtin_bit_cast(unsigned, p);
    }
    if (idx < L_ * G4) bbuf[idx] = bih[idx] + bhh[idx];
}

__global__ __launch_bounds__(TPB, 1) void lstm_stack_kernel(
    const float* __restrict__ x,      // [B,T,34]
    const uint4* __restrict__ w2,     // packed f16x2 weights
    const float* __restrict__ bbuf,   // [10][320]
    const float* __restrict__ fcw,    // [5,80]
    const float* __restrict__ fcb,    // [5]
    float* __restrict__ out)          // [B,5]
{
    const int b   = blockIdx.x;
    const int tid = threadIdx.x;      // 0..639
    const int e   = tid >> 3;         // h element 0..79
    const int s   = tid & 7;          // K slice (0-3: input side, 4-7: hidden side)
    const int sg  = s & 3;            // this lane's gate after distribute: 0=i 1=f 2=g 3=o

    // per-lane activation constants: sigm for i/f/o, tanh(x)=2*sigm(2x)-1 for g
    const float mA  = (sg == 2) ? -2.885390082f : -1.442695041f;   // -k*log2(e)
    const float bA  = (sg == 2) ? 2.f : 1.f;
    const float cA0 = (sg == 2) ? -1.f : 0.f;
    const bool  sel1 = (s & 1) != 0;
    const bool  sel2 = (s & 2) != 0;

    __shared__ __align__(16) _Float16 hist[T_][HP];   // 86 KB: x (f16) then h history, padded rows
    __shared__ __align__(16) _Float16 hs[2][H_];      // h(t-1) ping-pong

    // ---- stage x -> f16 hist (zero-pad 34..79; cols 80..83 never read) ----
    for (int j = tid; j < T_ * H_; j += TPB) {
        int t = j / H_, k = j % H_;
        float v = (k < IN_) ? x[((size_t)b * T_ + t) * IN_ + k] : 0.f;
        hist[t][k] = (_Float16)v;
    }

    for (int l = 0; l < L_; ++l) {
        // ---- weights for this layer: 10 coalesced uint4 loads, resident all layer ----
        const uint4* wp = w2 + (size_t)l * 10 * TPB + tid;
        uint4 W0 = wp[0 * TPB], W1 = wp[1 * TPB], W2 = wp[2 * TPB], W3 = wp[3 * TPB], W4 = wp[4 * TPB];
        uint4 W5 = wp[5 * TPB], W6 = wp[6 * TPB], W7 = wp[7 * TPB], W8 = wp[8 * TPB], W9 = wp[9 * TPB];

        const float bi = (s == 0) ? bbuf[l * G4 + 0 * H_ + e] : 0.f;
        const float bf = (s == 0) ? bbuf[l * G4 + 1 * H_ + e] : 0.f;
        const float bg = (s == 0) ? bbuf[l * G4 + 2 * H_ + e] : 0.f;
        const float bo = (s == 0) ? bbuf[l * G4 + 3 * H_ + e] : 0.f;

        if (tid < 40) ((unsigned*)&hs[0][0])[tid] = 0;   // h(-1) = 0 (80 f16)
        __syncthreads();

        float cold = 0.f;
        _Float16 h16 = (_Float16)0.f;
        int par = 0;

#pragma unroll 2
        for (int t = 0; t < T_; ++t) {
            if (t && s == 1) hist[t - 1][e] = h16;   // deferred history write (safe: t-1 consumed)

            const h4* vp = (s < 4) ? (const h4*)(&hist[t][0] + 20 * s)
                                   : (const h4*)(&hs[par][0] + 20 * (s - 4));
            h4 v0 = vp[0], v1 = vp[1], v2 = vp[2], v3 = vp[3], v4 = vp[4];
            h2 p0 = lo2(v0), p1 = hi2(v0), p2 = lo2(v1), p3 = hi2(v1), p4 = lo2(v2);
            h2 p5 = hi2(v2), p6 = lo2(v3), p7 = hi2(v3), p8 = lo2(v4), p9 = hi2(v4);

            float aI = bi, aF = bf, aG = bg, aO = bo;
#define D(acc, W, C, P) acc = __builtin_amdgcn_fdot2(bc(W.C), P, acc, false);
            D(aI, W0, x, p0) D(aI, W0, y, p1) D(aI, W0, z, p2) D(aI, W0, w, p3)
            D(aI, W1, x, p4) D(aI, W1, y, p5) D(aI, W1, z, p6) D(aI, W1, w, p7)
            D(aI, W2, x, p8) D(aI, W2, y, p9)
            D(aF, W2, z, p0) D(aF, W2, w, p1)
            D(aF, W3, x, p2) D(aF, W3, y, p3) D(aF, W3, z, p4) D(aF, W3, w, p5)
            D(aF, W4, x, p6) D(aF, W4, y, p7) D(aF, W4, z, p8) D(aF, W4, w, p9)
            D(aG, W5, x, p0) D(aG, W5, y, p1) D(aG, W5, z, p2) D(aG, W5, w, p3)
            D(aG, W6, x, p4) D(aG, W6, y, p5) D(aG, W6, z, p6) D(aG, W6, w, p7)
            D(aG, W7, x, p8) D(aG, W7, y, p9)
            D(aO, W7, z, p0) D(aO, W7, w, p1)
            D(aO, W8, x, p2) D(aO, W8, y, p3) D(aO, W8, z, p4) D(aO, W8, w, p5)
            D(aO, W9, x, p6) D(aO, W9, y, p7) D(aO, W9, z, p8) D(aO, W9, w, p9)
#undef D
            // ---- distribute-reduce: lane s ends with 8-lane total of gate (s&3) ----
            float kI = sel1 ? aF : aI, oI = sel1 ? aI : aF;
            float AIF = kI + dpp_mov<0xB1>(oI);            // xor1 pair-sum of my kept gate
            float kG = sel1 ? aO : aG, oG = sel1 ? aG : aO;
            float BGO = kG + dpp_mov<0xB1>(oG);
            float k2v = sel2 ? BGO : AIF, o2 = sel2 ? AIF : BGO;
            float S = k2v + dpp_mov<0x4E>(o2);             // xor2: 4-lane sum of gate s&3
            S = S + dpp_mov<0x1B>(dpp_mov<0x141>(S));      // xor4 (= xor7 then xor3): 8-lane total

            // ---- this lane's gate activation only (2 trans) ----
            float y   = __builtin_amdgcn_rcpf(1.f + __builtin_amdgcn_exp2f(mA * S));
            float act = __builtin_fmaf(bA, y, cA0);

            // ---- c/h update in f-lanes via quad DPP exchanges ----
            float t2v  = dpp_mov<0x4E>(act);               // act[u^2]: i<-g, f<-o
            float prod = act * t2v;                        // i-lanes: i*g
            float t3v  = dpp_mov<0xB1>(prod);              // f-lanes receive i*g
            float cnew = __builtin_fmaf(act, cold, t3v);   // f-lanes: f*c + i*g
            float th   = __builtin_fmaf(2.f,
                           __builtin_amdgcn_rcpf(1.f + __builtin_amdgcn_exp2f(-2.885390082f * cnew)),
                           -1.f);                          // tanh(cnew)
            float h = t2v * th;                            // f-lanes: o * tanh(c)
            h16 = (_Float16)h;
            cold = cnew;

            if (s == 1) hs[par ^ 1][e] = h16;
            __syncthreads();
            par ^= 1;
        }
        if (s == 1) hist[T_ - 1][e] = h16;   // flush last step
        __syncthreads();
    }

    // ---- fc on final hidden state ----
    if (tid < NC_) {
        float acc = fcb[tid];
#pragma unroll
        for (int j = 0; j < H_; ++j) acc += fcw[tid * H_ + j] * (float)hist[T_ - 1][j];
        out[b * NC_ + tid] = acc;
    }
}

extern "C" void kernel_launch(void* const* d_in, const int* in_sizes, int n_in,
                              void* d_out, int out_size, void* d_ws, size_t ws_size,
                              hipStream_t stream) {
    const float* x    = (const float*)d_in[0];
    const float* Wih0 = (const float*)d_in[1];
    const float* WihR = (const float*)d_in[2];
    const float* Whh  = (const float*)d_in[3];
    const float* bih  = (const float*)d_in[4];
    const float* bhh  = (const float*)d_in[5];
    const float* fcw  = (const float*)d_in[6];
    const float* fcb  = (const float*)d_in[7];

    unsigned* w2 = (unsigned*)d_ws;           // 256000 dwords
    float* bbuf  = (float*)(w2 + 256000);     // 3200 floats

    prep_kernel<<<dim3(1000), dim3(256), 0, stream>>>(
        Wih0, WihR, Whh, bih, bhh, w2, bbuf);

    lstm_stack_kernel<<<dim3(B_), dim3(TPB), 0, stream>>>(
        x, (const uint4*)w2, bbuf, fcw, fcb, (float*)d_out);
}